// Round 20
// baseline (190.625 us; speedup 1.0000x reference)
//
#include <hip/hip_runtime.h>
#include <math.h>
#include <stdint.h>

typedef __attribute__((ext_vector_type(8))) _Float16 f16x8;
typedef __attribute__((ext_vector_type(2))) __fp16 fp16x2;
typedef __attribute__((ext_vector_type(4))) float f32x4;
typedef __attribute__((ext_vector_type(16))) float f32x16;

static __device__ __forceinline__ unsigned short f2h(float f) {
  union { _Float16 h; unsigned short u; } v; v.h = (_Float16)f;
  return v.u;
}
static __device__ __forceinline__ float h2f(unsigned short u) {
  union { unsigned short u; _Float16 h; } v; v.u = u;
  return (float)v.h;
}
static __device__ __forceinline__ unsigned pkrtz(float a, float b) {
  union { fp16x2 h; unsigned u; } v;
  v.h = __builtin_amdgcn_cvt_pkrtz(a, b);
  return v.u;
}

#define GLOAD_LDS16(g, l) __builtin_amdgcn_global_load_lds( \
    (const __attribute__((address_space(1))) void*)(g),     \
    (__attribute__((address_space(3))) void*)(l), 16, 0, 0)

// ---------------- pack weights (all 4 sets in one dispatch): W2 = [[Wr,-Wi],[Wi,Wr]] ----------------
__global__ __launch_bounds__(256) void pack_w4(
    const float* __restrict__ Wr0, const float* __restrict__ Wi0,
    const float* __restrict__ br0, const float* __restrict__ bi0,
    const float* __restrict__ Wr1, const float* __restrict__ Wi1,
    const float* __restrict__ br1, const float* __restrict__ bi1,
    const float* __restrict__ Wr2, const float* __restrict__ Wi2,
    const float* __restrict__ br2, const float* __restrict__ bi2,
    const float* __restrict__ Wr3, const float* __restrict__ Wi3,
    const float* __restrict__ br3, const float* __restrict__ bi3,
    unsigned short* __restrict__ W2, float* __restrict__ bias2) {
  const int s = blockIdx.y;
  const float* Wr = (s == 0) ? Wr0 : (s == 1) ? Wr1 : (s == 2) ? Wr2 : Wr3;
  const float* Wi = (s == 0) ? Wi0 : (s == 1) ? Wi1 : (s == 2) ? Wi2 : Wi3;
  const float* br = (s == 0) ? br0 : (s == 1) ? br1 : (s == 2) ? br2 : br3;
  const float* bi = (s == 0) ? bi0 : (s == 1) ? bi1 : (s == 2) ? bi2 : bi3;
  W2 += (size_t)s * 1024 * 1024;
  bias2 += s * 1024;
  int idx = blockIdx.x * 256 + threadIdx.x;
  int m = idx >> 10, k = idx & 1023;
  int o = m & 511, d = k & 511;
  float v;
  if (m < 512) v = (k < 512) ? Wr[o * 512 + d] : -Wi[o * 512 + d];
  else         v = (k < 512) ? Wi[o * 512 + d] :  Wr[o * 512 + d];
  W2[idx] = f2h(v);
  if (idx < 1024) {
    int oo = idx & 511;
    bias2[idx] = (idx < 512) ? (br[oo] - bi[oo]) : (br[oo] + bi[oo]);
  }
}

// ---------------- pack x: (B,D,2,S) f32 -> XT[(b*2048+s)][(c*512+d)] f16 (B^T layout) ----------------
__global__ __launch_bounds__(256) void pack_x(
    const float* __restrict__ x, unsigned short* __restrict__ XT) {
  __shared__ unsigned short tl[64][72];
  const int t = threadIdx.x;
  const int sBase = blockIdx.x * 64, dBase = blockIdx.y * 64;
  const int b = blockIdx.z >> 1, c = blockIdx.z & 1;
  const int r = t >> 2, cb = (t & 3) * 16;
  const float* src = x + (((size_t)(b * 512 + dBase + r) * 2 + c) * 2048 + sBase + cb);
#pragma unroll
  for (int j = 0; j < 16; j += 4) {
    float4 v = *(const float4*)(src + j);
    tl[cb + j + 0][r] = f2h(v.x);
    tl[cb + j + 1][r] = f2h(v.y);
    tl[cb + j + 2][r] = f2h(v.z);
    tl[cb + j + 3][r] = f2h(v.w);
  }
  __syncthreads();
  const int s = t >> 2, dc = (t & 3) * 16;
  unsigned short* dst = XT + ((size_t)(b * 2048 + sBase + s)) * 1024 + c * 512 + dBase + dc;
  *(uint4*)dst = *(const uint4*)&tl[s][dc];
  *(uint4*)(dst + 8) = *(const uint4*)&tl[s][dc + 8];
}

// ---------------- GEMM + fused magnitude epilogue ----------------
// BK=64, XOR-swizzled staging (linear LDS dest, permuted global source chunk,
// matching XOR on ds_read). z=0: Q (mag epilogue -> Qm row-major); z=1: K (mag ->
// Km fragment-major); z=2: V fragment-major. MODE 1: fp32 scattered into d_out.
template <int MODE>
__global__ __launch_bounds__(256) void gemm_bt(
    const unsigned short* __restrict__ A, const unsigned short* __restrict__ Bt,
    const float* __restrict__ bias,
    unsigned short* __restrict__ Qo, unsigned short* __restrict__ Ko,
    unsigned short* __restrict__ Vo, float* __restrict__ Cf) {
  __shared__ unsigned short SH[16384];
  const int t = threadIdx.x;
  const int wave = t >> 6, lane = t & 63;
  const int wr = wave >> 1, wc = wave & 1;
  const int bid = blockIdx.x;
  const int xcd = bid & 7, g = bid >> 3;
  const int i = g & 63, z = g >> 6;
  const int nb = xcd * 8 + (i >> 3), mb = i & 7;
  const int nBase = nb * 128;
  A += (size_t)z * 1024 * 1024;
  bias += z * 1024;
  const int lr = lane & 15, hi16 = lane >> 4;
  f32x4 acc[4][4] = {};
  const int c = wave * 8 + (lane >> 3);
  const int colsw = ((lane & 7) ^ (c & 7)) * 8;
  const unsigned short* gaBase;
  size_t gaStride;
  if (MODE == 0 && z < 2) {
    gaBase = A + (size_t)(mb * 64 + (c & 15) + ((c >> 4) & 1) * 512) * 1024 + colsw;
    gaStride = (size_t)16 * 1024;
  } else {
    gaBase = A + (size_t)(mb * 128 + c) * 1024 + colsw;
    gaStride = (size_t)32 * 1024;
  }
  const unsigned short* gbBase = Bt + (size_t)(nBase + c) * 1024 + colsw;
  for (int k0 = 0; k0 < 1024; k0 += 64) {
    __syncthreads();
#pragma unroll
    for (int is = 0; is < 4; ++is) {
      GLOAD_LDS16(gaBase + is * gaStride + k0, &SH[is * 2048 + wave * 512]);
      GLOAD_LDS16(gbBase + (size_t)is * 32 * 1024 + k0, &SH[8192 + is * 2048 + wave * 512]);
    }
    __syncthreads();
#pragma unroll
    for (int kh = 0; kh < 2; ++kh) {
      f16x8 af[4], bfr[4];
#pragma unroll
      for (int i2 = 0; i2 < 4; ++i2) {
        const int rowA = wr * 64 + i2 * 16 + lr;
        const int rowB = wc * 64 + i2 * 16 + lr;
        const int sl = kh * 4 + hi16;
        af[i2]  = *(const f16x8*)&SH[rowA * 64 + ((sl ^ (rowA & 7)) * 8)];
        bfr[i2] = *(const f16x8*)&SH[8192 + rowB * 64 + ((sl ^ (rowB & 7)) * 8)];
      }
#pragma unroll
      for (int i2 = 0; i2 < 4; ++i2)
#pragma unroll
        for (int j = 0; j < 4; ++j)
          acc[i2][j] = __builtin_amdgcn_mfma_f32_16x16x32_f16(af[i2], bfr[j], acc[i2][j], 0, 0, 0);
    }
  }
  const int cr = hi16 * 4, cc = lane & 15;
  if (MODE == 0 && z < 2) {
    __syncthreads();
    unsigned short (*mg)[72] = (unsigned short(*)[72])SH;
#pragma unroll
    for (int u = 0; u < 2; ++u) {
#pragma unroll
      for (int j = 0; j < 4; ++j) {
        const int ssL = wc * 64 + j * 16 + cc;
#pragma unroll
        for (int g2 = 0; g2 < 4; ++g2) {
          const int dl = wr * 32 + u * 16 + cr + g2;
          const int o = mb * 64 + dl;
          float vr_ = acc[2 * u][j][g2] + bias[o];
          float vi_ = acc[2 * u + 1][j][g2] + bias[512 + o];
          mg[ssL][dl] = f2h(sqrtf(vr_ * vr_ + vi_ * vi_ + 1e-8f));
        }
      }
    }
    __syncthreads();
    const int bq = nBase >> 11;
    const int bh = bq * 8 + mb;
    const int ssBase = nBase & 2047;
    if (z == 0) {
      unsigned short* Out = Qo + ((size_t)bh * 2048 + ssBase) * 64;
#pragma unroll
      for (int r = 0; r < 4; ++r) {
        const int idx = t + 256 * r;
        const int row = idx >> 3, e8 = idx & 7;
        *(uint4*)(Out + (size_t)row * 64 + e8 * 8) = *(const uint4*)&mg[row][e8 * 8];
      }
    } else {
      const int tile0 = ssBase >> 6;
#pragma unroll
      for (int r = 0; r < 4; ++r) {
        const int idx = t + 256 * r;
        const int q31 = idx & 31, chunk = idx >> 5;
        const int hi2 = chunk & 1, db = (chunk >> 1) & 3;
        const int kb = (chunk >> 3) & 1, tl_ = chunk >> 4;
        const int ssL = tl_ * 64 + kb * 32 + q31;
        const size_t dst =
            ((((size_t)bh * 32 + tile0 + tl_) * 2 + kb) * 4 + db) * 512 + hi2 * 256 + q31 * 8;
        *(uint4*)(Ko + dst) = *(const uint4*)&mg[ssL][db * 16 + hi2 * 8];
      }
    }
  } else {
#pragma unroll
    for (int i2 = 0; i2 < 4; ++i2) {
#pragma unroll
      for (int j = 0; j < 4; ++j) {
        const int m0 = mb * 128 + wr * 64 + i2 * 16 + cr;
        const int n0 = nBase + wc * 64 + j * 16 + cc;
#pragma unroll
        for (int g2 = 0; g2 < 4; ++g2) {
          float v = acc[i2][j][g2] + bias[m0 + g2];
          if (MODE == 0) {
            const int m = m0 + g2;
            const int ri = m >> 9, mm = m & 511;
            const int h = mm >> 6, dloc = mm & 63;
            const int jj = dloc >> 5, q31 = dloc & 31;
            const int b = n0 >> 11, s = n0 & 2047;
            const int tile = s >> 6, ks = (s >> 4) & 3, hi = (s >> 3) & 1, e = s & 7;
            const size_t flat =
                ((((((size_t)(b * 8 + h) * 32 + tile) * 4 + ks) * 2 + jj) * 2 + ri) * 64 +
                 hi * 32 + q31) * 8 + e;
            Vo[flat] = f2h(v);
          } else {
            const int m = m0 + g2;
            const int cch = m >> 9, o = m & 511;
            const int b = n0 >> 11, s = n0 & 2047;
            Cf[(size_t)b * 2097152 + (size_t)o * 4096 + cch * 2048 + s] = v;
          }
        }
      }
    }
  }
}

// ---------------- flash attention (R14/R18 known-best): swapped 32x32, fragment-major K/V ----------------
__global__ __launch_bounds__(256) void attn(
    const unsigned short* __restrict__ Qm, const unsigned short* __restrict__ Km,
    const unsigned short* __restrict__ Vf, unsigned short* __restrict__ OutT) {
  const int t = threadIdx.x, wave = t >> 6, lane = t & 63;
  const int id = blockIdx.x;
  const int xcd = id & 7, within = id >> 3;
  const int bh = xcd * 4 + (within >> 4);
  const int qtile = within & 15;
  const int b = bh >> 3, h = bh & 7;
  const int q31 = lane & 31, hi = lane >> 5;
  const int qBase = qtile * 128 + wave * 32;
  const float ls = 0.18033688f;  // log2(e)/sqrt(DK)

  f16x8 qf[4];
  {
    const unsigned short* qp = Qm + ((size_t)bh * 2048 + qBase + q31) * 64 + hi * 8;
    qf[0] = *(const f16x8*)qp;
    qf[1] = *(const f16x8*)(qp + 16);
    qf[2] = *(const f16x8*)(qp + 32);
    qf[3] = *(const f16x8*)(qp + 48);
  }
  f32x16 Or[2] = {}, Oi[2] = {};
  float m = -1e30f, l = 0.f;

  const unsigned short* kmF = Km + (size_t)bh * 131072 + (size_t)lane * 8;
  const unsigned short* vF  = Vf + (size_t)bh * 262144 + (size_t)lane * 8;

  for (int t0 = 0; t0 < 2048; t0 += 64) {
    const int tile = t0 >> 6;
    f16x8 kf[2][4];
#pragma unroll
    for (int kb = 0; kb < 2; ++kb)
#pragma unroll
      for (int db = 0; db < 4; ++db)
        kf[kb][db] = *(const f16x8*)(kmF + (size_t)(((tile * 2 + kb) * 4 + db)) * 512);
    __builtin_amdgcn_sched_barrier(0);
    f32x16 S[2] = {};
#pragma unroll
    for (int kb = 0; kb < 2; ++kb)
#pragma unroll
      for (int db = 0; db < 4; ++db)
        S[kb] = __builtin_amdgcn_mfma_f32_32x32x16_f16(kf[kb][db], qf[db], S[kb], 0, 0, 0);
    f16x8 vr[4][2], vi[4][2];
#pragma unroll
    for (int ks = 0; ks < 4; ++ks)
#pragma unroll
      for (int j = 0; j < 2; ++j) {
        const size_t u = (size_t)(((tile * 4 + ks) * 2 + j) * 2) * 512;
        vr[ks][j] = *(const f16x8*)(vF + u);
        vi[ks][j] = *(const f16x8*)(vF + u + 512);
      }
    __builtin_amdgcn_sched_barrier(0);
    float m0a = fmaxf(S[0][0], S[0][1]), m0b = fmaxf(S[0][2], S[0][3]);
#pragma unroll
    for (int r = 4; r < 16; r += 4) {
      m0a = fmaxf(m0a, fmaxf(S[0][r], S[0][r + 1]));
      m0b = fmaxf(m0b, fmaxf(S[0][r + 2], S[0][r + 3]));
    }
#pragma unroll
    for (int r = 0; r < 16; r += 4) {
      m0a = fmaxf(m0a, fmaxf(S[1][r], S[1][r + 1]));
      m0b = fmaxf(m0b, fmaxf(S[1][r + 2], S[1][r + 3]));
    }
    float vmax = fmaxf(m0a, m0b);
    vmax = fmaxf(vmax, __shfl_xor(vmax, 32, 64));
    float pmax = vmax * ls;
    if (__any(pmax > m + 8.0f)) {
      float mnew = fmaxf(m, pmax);
      float al = __builtin_amdgcn_exp2f(m - mnew);
      m = mnew;
      l *= al;
#pragma unroll
      for (int r = 0; r < 16; ++r) {
        const int qloc = (r & 3) + 8 * (r >> 2) + 4 * hi;
        float ao = __shfl(al, qloc, 64);
        Or[0][r] *= ao; Or[1][r] *= ao;
        Oi[0][r] *= ao; Oi[1][r] *= ao;
      }
    }
    float p[2][16];
    float ps0 = 0.f, ps1 = 0.f;
#pragma unroll
    for (int kb = 0; kb < 2; ++kb)
#pragma unroll
      for (int r = 0; r < 16; r += 2) {
        float pa_ = __builtin_amdgcn_exp2f(fmaf(S[kb][r], ls, -m));
        float pb_ = __builtin_amdgcn_exp2f(fmaf(S[kb][r + 1], ls, -m));
        p[kb][r] = pa_; p[kb][r + 1] = pb_;
        ps0 += pa_; ps1 += pb_;
      }
    float ps = ps0 + ps1;
    ps += __shfl_xor(ps, 32, 64);
    l += ps;
    f16x8 pa[4];
#pragma unroll
    for (int ks = 0; ks < 4; ++ks) {
      const float* pp = &p[ks >> 1][8 * (ks & 1)];
      unsigned c0 = pkrtz(pp[0], pp[1]);
      unsigned c1 = pkrtz(pp[2], pp[3]);
      unsigned d0 = pkrtz(pp[4], pp[5]);
      unsigned d1 = pkrtz(pp[6], pp[7]);
      asm volatile("v_permlane32_swap_b32 %0, %1" : "+v"(c0), "+v"(d0));
      asm volatile("v_permlane32_swap_b32 %0, %1" : "+v"(c1), "+v"(d1));
      union { unsigned u[4]; f16x8 v; } w;
      w.u[0] = c0; w.u[1] = c1; w.u[2] = d0; w.u[3] = d1;
      pa[ks] = w.v;
    }
#pragma unroll
    for (int ks = 0; ks < 4; ++ks)
#pragma unroll
      for (int j = 0; j < 2; ++j) {
        Or[j] = __builtin_amdgcn_mfma_f32_32x32x16_f16(pa[ks], vr[ks][j], Or[j], 0, 0, 0);
        Oi[j] = __builtin_amdgcn_mfma_f32_32x32x16_f16(pa[ks], vi[ks][j], Oi[j], 0, 0, 0);
      }
  }
  float linv = 1.0f / l;
#pragma unroll
  for (int r = 0; r < 16; ++r) {
    const int qloc = (r & 3) + 8 * (r >> 2) + 4 * hi;
    float iv = __shfl(linv, qloc, 64);
    unsigned short* orow = OutT + ((size_t)b * 2048 + qBase + qloc) * 1024 + h * 64;
    orow[q31]       = f2h(Or[0][r] * iv);
    orow[32 + q31]  = f2h(Or[1][r] * iv);
    orow[512 + q31] = f2h(Oi[0][r] * iv);
    orow[544 + q31] = f2h(Oi[1][r] * iv);
  }
}

extern "C" void kernel_launch(void* const* d_in, const int* in_sizes, int n_in,
                              void* d_out, int out_size, void* d_ws, size_t ws_size,
                              hipStream_t stream) {
  (void)in_sizes; (void)n_in; (void)out_size; (void)ws_size;
  const float* x = (const float*)d_in[0];

  // workspace layout: XT 16.78M | W2 8.39M | bias2 16K | Cqkv 50.33M  => ~75.5 MB
  unsigned short* XT = (unsigned short*)d_ws;
  unsigned short* W2 = XT + (size_t)8192 * 1024;
  float* bias2 = (float*)(W2 + (size_t)4 * 1024 * 1024);
  unsigned short* Cqkv = (unsigned short*)(bias2 + 4096);
  // Qm/Km live in d_out (dead before final GEMM overwrites d_out)
  unsigned short* Qm = (unsigned short*)d_out;
  unsigned short* Km = Qm + (size_t)4 * 8 * 2048 * 64;   // Km_f fragment-major
  // V_f in the z=2 slab of Cqkv; OutT reuses Cq slab
  unsigned short* Vf = Cqkv + (size_t)2 * 1024 * 8192;
  unsigned short* OutT = Cqkv;

  pack_w4<<<dim3(4096, 4), 256, 0, stream>>>(
      (const float*)d_in[1],  (const float*)d_in[2],  (const float*)d_in[3],  (const float*)d_in[4],
      (const float*)d_in[5],  (const float*)d_in[6],  (const float*)d_in[7],  (const float*)d_in[8],
      (const float*)d_in[9],  (const float*)d_in[10], (const float*)d_in[11], (const float*)d_in[12],
      (const float*)d_in[13], (const float*)d_in[14], (const float*)d_in[15], (const float*)d_in[16],
      W2, bias2);
  pack_x<<<dim3(32, 8, 8), 256, 0, stream>>>(x, XT);
  gemm_bt<0><<<1536, 256, 0, stream>>>(W2, XT, bias2, Qm, Km, Vf, nullptr);
  attn<<<512, 256, 0, stream>>>(Qm, Km, Vf, OutT);
  gemm_bt<1><<<512, 256, 0, stream>>>(
      W2 + (size_t)3 * 1024 * 1024, OutT, bias2 + 3 * 1024, nullptr, nullptr, nullptr,
      (float*)d_out);
}

// Round 21
// 187.639 us; speedup vs baseline: 1.0159x; 1.0159x over previous
//
#include <hip/hip_runtime.h>
#include <math.h>
#include <stdint.h>

typedef __attribute__((ext_vector_type(8))) _Float16 f16x8;
typedef __attribute__((ext_vector_type(2))) __fp16 fp16x2;
typedef __attribute__((ext_vector_type(4))) float f32x4;
typedef __attribute__((ext_vector_type(16))) float f32x16;

static __device__ __forceinline__ unsigned short f2h(float f) {
  union { _Float16 h; unsigned short u; } v; v.h = (_Float16)f;
  return v.u;
}
static __device__ __forceinline__ float h2f(unsigned short u) {
  union { unsigned short u; _Float16 h; } v; v.u = u;
  return (float)v.h;
}
static __device__ __forceinline__ unsigned pkrtz(float a, float b) {
  union { fp16x2 h; unsigned u; } v;
  v.h = __builtin_amdgcn_cvt_pkrtz(a, b);
  return v.u;
}

#define GLOAD_LDS16(g, l) __builtin_amdgcn_global_load_lds( \
    (const __attribute__((address_space(1))) void*)(g),     \
    (__attribute__((address_space(3))) void*)(l), 16, 0, 0)

// ---------------- pack weights (all 4 sets in one dispatch): W2 = [[Wr,-Wi],[Wi,Wr]] ----------------
__global__ __launch_bounds__(256) void pack_w4(
    const float* __restrict__ Wr0, const float* __restrict__ Wi0,
    const float* __restrict__ br0, const float* __restrict__ bi0,
    const float* __restrict__ Wr1, const float* __restrict__ Wi1,
    const float* __restrict__ br1, const float* __restrict__ bi1,
    const float* __restrict__ Wr2, const float* __restrict__ Wi2,
    const float* __restrict__ br2, const float* __restrict__ bi2,
    const float* __restrict__ Wr3, const float* __restrict__ Wi3,
    const float* __restrict__ br3, const float* __restrict__ bi3,
    unsigned short* __restrict__ W2, float* __restrict__ bias2) {
  const int s = blockIdx.y;
  const float* Wr = (s == 0) ? Wr0 : (s == 1) ? Wr1 : (s == 2) ? Wr2 : Wr3;
  const float* Wi = (s == 0) ? Wi0 : (s == 1) ? Wi1 : (s == 2) ? Wi2 : Wi3;
  const float* br = (s == 0) ? br0 : (s == 1) ? br1 : (s == 2) ? br2 : br3;
  const float* bi = (s == 0) ? bi0 : (s == 1) ? bi1 : (s == 2) ? bi2 : bi3;
  W2 += (size_t)s * 1024 * 1024;
  bias2 += s * 1024;
  int idx = blockIdx.x * 256 + threadIdx.x;
  int m = idx >> 10, k = idx & 1023;
  int o = m & 511, d = k & 511;
  float v;
  if (m < 512) v = (k < 512) ? Wr[o * 512 + d] : -Wi[o * 512 + d];
  else         v = (k < 512) ? Wi[o * 512 + d] :  Wr[o * 512 + d];
  W2[idx] = f2h(v);
  if (idx < 1024) {
    int oo = idx & 511;
    bias2[idx] = (idx < 512) ? (br[oo] - bi[oo]) : (br[oo] + bi[oo]);
  }
}

// ---------------- pack x: (B,D,2,S) f32 -> XT[(b*2048+s)][(c*512+d)] f16 (B^T layout) ----------------
__global__ __launch_bounds__(256) void pack_x(
    const float* __restrict__ x, unsigned short* __restrict__ XT) {
  __shared__ unsigned short tl[64][72];
  const int t = threadIdx.x;
  const int sBase = blockIdx.x * 64, dBase = blockIdx.y * 64;
  const int b = blockIdx.z >> 1, c = blockIdx.z & 1;
  const int r = t >> 2, cb = (t & 3) * 16;
  const float* src = x + (((size_t)(b * 512 + dBase + r) * 2 + c) * 2048 + sBase + cb);
#pragma unroll
  for (int j = 0; j < 16; j += 4) {
    float4 v = *(const float4*)(src + j);
    tl[cb + j + 0][r] = f2h(v.x);
    tl[cb + j + 1][r] = f2h(v.y);
    tl[cb + j + 2][r] = f2h(v.z);
    tl[cb + j + 3][r] = f2h(v.w);
  }
  __syncthreads();
  const int s = t >> 2, dc = (t & 3) * 16;
  unsigned short* dst = XT + ((size_t)(b * 2048 + sBase + s)) * 1024 + c * 512 + dBase + dc;
  *(uint4*)dst = *(const uint4*)&tl[s][dc];
  *(uint4*)(dst + 8) = *(const uint4*)&tl[s][dc + 8];
}

// ---------------- GEMM + fused magnitude epilogue ----------------
// BK=64, XOR-swizzled staging (linear LDS dest, permuted global source chunk,
// matching XOR on ds_read). z=0: Q (mag epilogue -> Qm row-major); z=1: K (mag ->
// Km fragment-major); z=2: V fragment-major. MODE 1: fp32 scattered into d_out.
template <int MODE>
__global__ __launch_bounds__(256) void gemm_bt(
    const unsigned short* __restrict__ A, const unsigned short* __restrict__ Bt,
    const float* __restrict__ bias,
    unsigned short* __restrict__ Qo, unsigned short* __restrict__ Ko,
    unsigned short* __restrict__ Vo, float* __restrict__ Cf) {
  __shared__ unsigned short SH[16384];
  const int t = threadIdx.x;
  const int wave = t >> 6, lane = t & 63;
  const int wr = wave >> 1, wc = wave & 1;
  const int bid = blockIdx.x;
  const int xcd = bid & 7, g = bid >> 3;
  const int i = g & 63, z = g >> 6;
  const int nb = xcd * 8 + (i >> 3), mb = i & 7;
  const int nBase = nb * 128;
  A += (size_t)z * 1024 * 1024;
  bias += z * 1024;
  const int lr = lane & 15, hi16 = lane >> 4;
  f32x4 acc[4][4] = {};
  const int c = wave * 8 + (lane >> 3);
  const int colsw = ((lane & 7) ^ (c & 7)) * 8;
  const unsigned short* gaBase;
  size_t gaStride;
  if (MODE == 0 && z < 2) {
    gaBase = A + (size_t)(mb * 64 + (c & 15) + ((c >> 4) & 1) * 512) * 1024 + colsw;
    gaStride = (size_t)16 * 1024;
  } else {
    gaBase = A + (size_t)(mb * 128 + c) * 1024 + colsw;
    gaStride = (size_t)32 * 1024;
  }
  const unsigned short* gbBase = Bt + (size_t)(nBase + c) * 1024 + colsw;
  for (int k0 = 0; k0 < 1024; k0 += 64) {
    __syncthreads();
#pragma unroll
    for (int is = 0; is < 4; ++is) {
      GLOAD_LDS16(gaBase + is * gaStride + k0, &SH[is * 2048 + wave * 512]);
      GLOAD_LDS16(gbBase + (size_t)is * 32 * 1024 + k0, &SH[8192 + is * 2048 + wave * 512]);
    }
    __syncthreads();
#pragma unroll
    for (int kh = 0; kh < 2; ++kh) {
      f16x8 af[4], bfr[4];
#pragma unroll
      for (int i2 = 0; i2 < 4; ++i2) {
        const int rowA = wr * 64 + i2 * 16 + lr;
        const int rowB = wc * 64 + i2 * 16 + lr;
        const int sl = kh * 4 + hi16;
        af[i2]  = *(const f16x8*)&SH[rowA * 64 + ((sl ^ (rowA & 7)) * 8)];
        bfr[i2] = *(const f16x8*)&SH[8192 + rowB * 64 + ((sl ^ (rowB & 7)) * 8)];
      }
#pragma unroll
      for (int i2 = 0; i2 < 4; ++i2)
#pragma unroll
        for (int j = 0; j < 4; ++j)
          acc[i2][j] = __builtin_amdgcn_mfma_f32_16x16x32_f16(af[i2], bfr[j], acc[i2][j], 0, 0, 0);
    }
  }
  const int cr = hi16 * 4, cc = lane & 15;
  if (MODE == 0 && z < 2) {
    __syncthreads();
    unsigned short (*mg)[72] = (unsigned short(*)[72])SH;
#pragma unroll
    for (int u = 0; u < 2; ++u) {
#pragma unroll
      for (int j = 0; j < 4; ++j) {
        const int ssL = wc * 64 + j * 16 + cc;
#pragma unroll
        for (int g2 = 0; g2 < 4; ++g2) {
          const int dl = wr * 32 + u * 16 + cr + g2;
          const int o = mb * 64 + dl;
          float vr_ = acc[2 * u][j][g2] + bias[o];
          float vi_ = acc[2 * u + 1][j][g2] + bias[512 + o];
          mg[ssL][dl] = f2h(sqrtf(vr_ * vr_ + vi_ * vi_ + 1e-8f));
        }
      }
    }
    __syncthreads();
    const int bq = nBase >> 11;
    const int bh = bq * 8 + mb;
    const int ssBase = nBase & 2047;
    if (z == 0) {
      unsigned short* Out = Qo + ((size_t)bh * 2048 + ssBase) * 64;
#pragma unroll
      for (int r = 0; r < 4; ++r) {
        const int idx = t + 256 * r;
        const int row = idx >> 3, e8 = idx & 7;
        *(uint4*)(Out + (size_t)row * 64 + e8 * 8) = *(const uint4*)&mg[row][e8 * 8];
      }
    } else {
      const int tile0 = ssBase >> 6;
#pragma unroll
      for (int r = 0; r < 4; ++r) {
        const int idx = t + 256 * r;
        const int q31 = idx & 31, chunk = idx >> 5;
        const int hi2 = chunk & 1, db = (chunk >> 1) & 3;
        const int kb = (chunk >> 3) & 1, tl_ = chunk >> 4;
        const int ssL = tl_ * 64 + kb * 32 + q31;
        const size_t dst =
            ((((size_t)bh * 32 + tile0 + tl_) * 2 + kb) * 4 + db) * 512 + hi2 * 256 + q31 * 8;
        *(uint4*)(Ko + dst) = *(const uint4*)&mg[ssL][db * 16 + hi2 * 8];
      }
    }
  } else {
#pragma unroll
    for (int i2 = 0; i2 < 4; ++i2) {
#pragma unroll
      for (int j = 0; j < 4; ++j) {
        const int m0 = mb * 128 + wr * 64 + i2 * 16 + cr;
        const int n0 = nBase + wc * 64 + j * 16 + cc;
#pragma unroll
        for (int g2 = 0; g2 < 4; ++g2) {
          float v = acc[i2][j][g2] + bias[m0 + g2];
          if (MODE == 0) {
            const int m = m0 + g2;
            const int ri = m >> 9, mm = m & 511;
            const int h = mm >> 6, dloc = mm & 63;
            const int jj = dloc >> 5, q31 = dloc & 31;
            const int b = n0 >> 11, s = n0 & 2047;
            const int tile = s >> 6, ks = (s >> 4) & 3, hi = (s >> 3) & 1, e = s & 7;
            const size_t flat =
                ((((((size_t)(b * 8 + h) * 32 + tile) * 4 + ks) * 2 + jj) * 2 + ri) * 64 +
                 hi * 32 + q31) * 8 + e;
            Vo[flat] = f2h(v);
          } else {
            const int m = m0 + g2;
            const int cch = m >> 9, o = m & 511;
            const int b = n0 >> 11, s = n0 & 2047;
            Cf[(size_t)b * 2097152 + (size_t)o * 4096 + cch * 2048 + s] = v;
          }
        }
      }
    }
  }
}

// ---------------- flash attention: R18 base + (proven-safe) max3 reduce & in-place S->P ----------------
__global__ __launch_bounds__(256) void attn(
    const unsigned short* __restrict__ Qm, const unsigned short* __restrict__ Km,
    const unsigned short* __restrict__ Vf, unsigned short* __restrict__ OutT) {
  const int t = threadIdx.x, wave = t >> 6, lane = t & 63;
  const int id = blockIdx.x;
  const int xcd = id & 7, within = id >> 3;
  const int bh = xcd * 4 + (within >> 4);
  const int qtile = within & 15;
  const int b = bh >> 3, h = bh & 7;
  const int q31 = lane & 31, hi = lane >> 5;
  const int qBase = qtile * 128 + wave * 32;
  const float ls = 0.18033688f;  // log2(e)/sqrt(DK)

  f16x8 qf[4];
  {
    const unsigned short* qp = Qm + ((size_t)bh * 2048 + qBase + q31) * 64 + hi * 8;
    qf[0] = *(const f16x8*)qp;
    qf[1] = *(const f16x8*)(qp + 16);
    qf[2] = *(const f16x8*)(qp + 32);
    qf[3] = *(const f16x8*)(qp + 48);
  }
  f32x16 Or[2] = {}, Oi[2] = {};
  float m = -1e30f, l = 0.f;

  const unsigned short* kmF = Km + (size_t)bh * 131072 + (size_t)lane * 8;
  const unsigned short* vF  = Vf + (size_t)bh * 262144 + (size_t)lane * 8;

  for (int t0 = 0; t0 < 2048; t0 += 64) {
    const int tile = t0 >> 6;
    f16x8 kf[2][4];
#pragma unroll
    for (int kb = 0; kb < 2; ++kb)
#pragma unroll
      for (int db = 0; db < 4; ++db)
        kf[kb][db] = *(const f16x8*)(kmF + (size_t)(((tile * 2 + kb) * 4 + db)) * 512);
    __builtin_amdgcn_sched_barrier(0);
    f32x16 S[2] = {};
#pragma unroll
    for (int kb = 0; kb < 2; ++kb)
#pragma unroll
      for (int db = 0; db < 4; ++db)
        S[kb] = __builtin_amdgcn_mfma_f32_32x32x16_f16(kf[kb][db], qf[db], S[kb], 0, 0, 0);
    f16x8 vr[4][2], vi[4][2];
#pragma unroll
    for (int ks = 0; ks < 4; ++ks)
#pragma unroll
      for (int j = 0; j < 2; ++j) {
        const size_t u = (size_t)(((tile * 4 + ks) * 2 + j) * 2) * 512;
        vr[ks][j] = *(const f16x8*)(vF + u);
        vi[ks][j] = *(const f16x8*)(vF + u + 512);
      }
    __builtin_amdgcn_sched_barrier(0);
    // ---- row max: max3-shaped chains (clang fuses fmax(fmax(a,b),c) -> v_max3_f32) ----
    float m0a = fmaxf(S[0][0], S[0][1]);
#pragma unroll
    for (int r = 2; r < 16; r += 2) m0a = fmaxf(fmaxf(m0a, S[0][r]), S[0][r + 1]);
    float m0b = fmaxf(S[1][0], S[1][1]);
#pragma unroll
    for (int r = 2; r < 16; r += 2) m0b = fmaxf(fmaxf(m0b, S[1][r]), S[1][r + 1]);
    float vmax = fmaxf(m0a, m0b);
    vmax = fmaxf(vmax, __shfl_xor(vmax, 32, 64));
    float pmax = vmax * ls;
    // ---- defer-max rescale (rare): al lives at lane=q, O rows are q=qloc -> shfl ----
    if (__any(pmax > m + 8.0f)) {
      float mnew = fmaxf(m, pmax);
      float al = __builtin_amdgcn_exp2f(m - mnew);
      m = mnew;
      l *= al;
#pragma unroll
      for (int r = 0; r < 16; ++r) {
        const int qloc = (r & 3) + 8 * (r >> 2) + 4 * hi;
        float ao = __shfl(al, qloc, 64);
        Or[0][r] *= ao; Or[1][r] *= ao;
        Oi[0][r] *= ao; Oi[1][r] *= ao;
      }
    }
    // ---- P in place: S = exp2(S*ls - m); lane-local sum (scalar l, as R18) ----
    float ps0 = 0.f, ps1 = 0.f;
#pragma unroll
    for (int kb = 0; kb < 2; ++kb)
#pragma unroll
      for (int r = 0; r < 16; r += 2) {
        float pa_ = __builtin_amdgcn_exp2f(fmaf(S[kb][r], ls, -m));
        float pb_ = __builtin_amdgcn_exp2f(fmaf(S[kb][r + 1], ls, -m));
        S[kb][r] = pa_; S[kb][r + 1] = pb_;
        ps0 += pa_; ps1 += pb_;
      }
    float ps = ps0 + ps1;
    ps += __shfl_xor(ps, 32, 64);
    l += ps;
    // ---- P (=S) -> PV A-frags: cvt_pkrtz + permlane32_swap ----
    f16x8 pa[4];
#pragma unroll
    for (int ks = 0; ks < 4; ++ks) {
      const int kb = ks >> 1, off = 8 * (ks & 1);
      unsigned c0 = pkrtz(S[kb][off + 0], S[kb][off + 1]);
      unsigned c1 = pkrtz(S[kb][off + 2], S[kb][off + 3]);
      unsigned d0 = pkrtz(S[kb][off + 4], S[kb][off + 5]);
      unsigned d1 = pkrtz(S[kb][off + 6], S[kb][off + 7]);
      asm volatile("v_permlane32_swap_b32 %0, %1" : "+v"(c0), "+v"(d0));
      asm volatile("v_permlane32_swap_b32 %0, %1" : "+v"(c1), "+v"(d1));
      union { unsigned u[4]; f16x8 v; } w;
      w.u[0] = c0; w.u[1] = c1; w.u[2] = d0; w.u[3] = d1;
      pa[ks] = w.v;
    }
    // ---- PV: O[j] += P x V, V already in registers ----
#pragma unroll
    for (int ks = 0; ks < 4; ++ks)
#pragma unroll
      for (int j = 0; j < 2; ++j) {
        Or[j] = __builtin_amdgcn_mfma_f32_32x32x16_f16(pa[ks], vr[ks][j], Or[j], 0, 0, 0);
        Oi[j] = __builtin_amdgcn_mfma_f32_32x32x16_f16(pa[ks], vi[ks][j], Oi[j], 0, 0, 0);
      }
  }
  float linv = 1.0f / l;
#pragma unroll
  for (int r = 0; r < 16; ++r) {
    const int qloc = (r & 3) + 8 * (r >> 2) + 4 * hi;
    float iv = __shfl(linv, qloc, 64);
    unsigned short* orow = OutT + ((size_t)b * 2048 + qBase + qloc) * 1024 + h * 64;
    orow[q31]       = f2h(Or[0][r] * iv);
    orow[32 + q31]  = f2h(Or[1][r] * iv);
    orow[512 + q31] = f2h(Oi[0][r] * iv);
    orow[544 + q31] = f2h(Oi[1][r] * iv);
  }
}

extern "C" void kernel_launch(void* const* d_in, const int* in_sizes, int n_in,
                              void* d_out, int out_size, void* d_ws, size_t ws_size,
                              hipStream_t stream) {
  (void)in_sizes; (void)n_in; (void)out_size; (void)ws_size;
  const float* x = (const float*)d_in[0];

  // workspace layout: XT 16.78M | W2 8.39M | bias2 16K | Cqkv 50.33M  => ~75.5 MB
  unsigned short* XT = (unsigned short*)d_ws;
  unsigned short* W2 = XT + (size_t)8192 * 1024;
  float* bias2 = (float*)(W2 + (size_t)4 * 1024 * 1024);
  unsigned short* Cqkv = (unsigned short*)(bias2 + 4096);
  // Qm/Km live in d_out (dead before final GEMM overwrites d_out)
  unsigned short* Qm = (unsigned short*)d_out;
  unsigned short* Km = Qm + (size_t)4 * 8 * 2048 * 64;   // Km_f fragment-major
  // V_f in the z=2 slab of Cqkv; OutT reuses Cq slab
  unsigned short* Vf = Cqkv + (size_t)2 * 1024 * 8192;
  unsigned short* OutT = Cqkv;

  pack_w4<<<dim3(4096, 4), 256, 0, stream>>>(
      (const float*)d_in[1],  (const float*)d_in[2],  (const float*)d_in[3],  (const float*)d_in[4],
      (const float*)d_in[5],  (const float*)d_in[6],  (const float*)d_in[7],  (const float*)d_in[8],
      (const float*)d_in[9],  (const float*)d_in[10], (const float*)d_in[11], (const float*)d_in[12],
      (const float*)d_in[13], (const float*)d_in[14], (const float*)d_in[15], (const float*)d_in[16],
      W2, bias2);
  pack_x<<<dim3(32, 8, 8), 256, 0, stream>>>(x, XT);
  gemm_bt<0><<<1536, 256, 0, stream>>>(W2, XT, bias2, Qm, Km, Vf, nullptr);
  attn<<<512, 256, 0, stream>>>(Qm, Km, Vf, OutT);
  gemm_bt<1><<<512, 256, 0, stream>>>(
      W2 + (size_t)3 * 1024 * 1024, OutT, bias2 + 3 * 1024, nullptr, nullptr, nullptr,
      (float*)d_out);
}